// Round 11
// baseline (173.941 us; speedup 1.0000x reference)
//
#include <hip/hip_runtime.h>
#include <math.h>

// QIM1D single-kernel: r = a*exp(-alpha*th)*sin(k*th)*cos(m*th) *
// |sum_i c_i*exp(i*w_i*th)|, minmax-normalized, +0.5, broadcast (B,1,L).
// L=2^21, B=4.
//
// R10 lesson: duration invariant to inst count (R2==R5), wg count (R5==R10
// at 2048 vs 256 wgs), occupancy (17 waves/CU == 1 wave/SIMD). No pipe is
// busy (VALUBusy 12.6%, ~0 HBM). Remaining theory: fixed per-graph-node
// dispatch/drain cost (~30-45us/node; R7: 143 = fills + 46.5 + ~46).
// R11 experiment: ONE kernel node total. Flag-spin grid sync (co-resident
// by construction), register-stashed r (no recompute), no memset node.

#define L_TOT   2097152
#define NT      256
#define NWG     512
#define CHUNKS  4                  // NWG*NT*CHUNKS*4 == L_TOT exactly
#define EPSF    1e-8f
#define FLT_BIG 3.402823466e38f
#define SENT    0x51B0F00Du        // != 0xAAAAAAAA poison

struct QimCoef {
    float cr[6], ci[6], w[6];
    float a, alpha, k, m;
};

__device__ __forceinline__ QimCoef setup_coeffs(
    float a, float alpha, float k, float m,
    const float* __restrict__ delta, const float* __restrict__ E,
    const float* __restrict__ uar, const float* __restrict__ uai,
    const float* __restrict__ ubr, const float* __restrict__ ubi)
{
    QimCoef q;
    float na2 = 0.f, nb2 = 0.f;
    float ar[6], ai_[6], br[6], bi_[6];
#pragma unroll
    for (int i = 0; i < 6; ++i) {
        ar[i] = uar[i]; ai_[i] = uai[i]; br[i] = ubr[i]; bi_[i] = ubi[i];
        na2 = fmaf(ar[i], ar[i], fmaf(ai_[i], ai_[i], na2));
        nb2 = fmaf(br[i], br[i], fmaf(bi_[i], bi_[i], nb2));
    }
    const float s = 1.f / ((__fsqrt_rn(na2) + EPSF) * (__fsqrt_rn(nb2) + EPSF));
#pragma unroll
    for (int i = 0; i < 6; ++i) {
        q.cr[i] = (br[i] * ar[i] + bi_[i] * ai_[i]) * s;
        q.ci[i] = (bi_[i] * ar[i] - br[i] * ai_[i]) * s;
        q.w[i]  = -(2.f * E[i] + delta[i]);
    }
    q.a = a; q.alpha = alpha; q.k = k; q.m = m;
    return q;
}

// r for 4 consecutive grid points: native-trans anchors + 3 small-angle
// rotation steps (h ~ 4.8e-7: sin x = x, cos x = 1 - x^2/2, f32-exact).
__device__ __forceinline__ void eval4(const QimCoef& q, int j0, float r[4])
{
    const float h   = 1.0f / (float)(L_TOT - 1);
    const float th0 = (float)j0 * h;

    float sk = __sinf(q.k * th0), ck = __cosf(q.k * th0);
    float sm = __sinf(q.m * th0), cm = __cosf(q.m * th0);
    float e  = q.a * __expf(-q.alpha * th0);

    const float skh = q.k * h, ckh = fmaf(-0.5f * skh, skh, 1.0f);
    const float smh = q.m * h, cmh = fmaf(-0.5f * smh, smh, 1.0f);
    const float eh  = __expf(-q.alpha * h);

    float sw[6], cw[6], swh[6], cwh[6];
#pragma unroll
    for (int i = 0; i < 6; ++i) {
        const float ph = q.w[i] * th0;
        sw[i]  = __sinf(ph);
        cw[i]  = __cosf(ph);
        swh[i] = q.w[i] * h;
        cwh[i] = fmaf(-0.5f * swh[i], swh[i], 1.0f);
    }

#pragma unroll
    for (int t = 0; t < 4; ++t) {
        float re = 0.f, im = 0.f;
#pragma unroll
        for (int i = 0; i < 6; ++i) {
            re = fmaf(q.cr[i], cw[i], fmaf(-q.ci[i], sw[i], re));
            im = fmaf(q.cr[i], sw[i], fmaf( q.ci[i], cw[i], im));
        }
        const float S = __fsqrt_rn(fmaf(re, re, im * im));
        r[t] = e * sk * cm * S;

        if (t < 3) {
            e *= eh;
            float ns, nc;
            ns = fmaf(sk, ckh,  ck * skh); nc = fmaf(ck, ckh, -sk * skh); sk = ns; ck = nc;
            ns = fmaf(sm, cmh,  cm * smh); nc = fmaf(cm, cmh, -sm * smh); sm = ns; cm = nc;
#pragma unroll
            for (int i = 0; i < 6; ++i) {
                ns = fmaf(sw[i], cwh[i],  cw[i] * swh[i]);
                nc = fmaf(cw[i], cwh[i], -sw[i] * swh[i]);
                sw[i] = ns; cw[i] = nc;
            }
        }
    }
}

__device__ __forceinline__ void block_minmax(float lmin, float lmax,
                                             float* out_min, float* out_max)
{
#pragma unroll
    for (int off = 32; off > 0; off >>= 1) {
        lmin = fminf(lmin, __shfl_down(lmin, off, 64));
        lmax = fmaxf(lmax, __shfl_down(lmax, off, 64));
    }
    __shared__ float smin[NT / 64], smax[NT / 64];
    const int lane = threadIdx.x & 63, wid = threadIdx.x >> 6;
    if (lane == 0) { smin[wid] = lmin; smax[wid] = lmax; }
    __syncthreads();
    if (threadIdx.x == 0) {
        float mn = smin[0], mx = smax[0];
#pragma unroll
        for (int i = 1; i < NT / 64; ++i) { mn = fminf(mn, smin[i]); mx = fmaxf(mx, smax[i]); }
        *out_min = mn; *out_max = mx;
    }
}

// ONE kernel: eval (stash r in regs) -> block minmax -> flag-release ->
// grid-wide spin (all NWG wgs co-resident: 512 wgs, <=2/CU launched,
// capacity ~8/CU at this VGPR/LDS) -> every block folds NWG partials ->
// normalize stashed r -> broadcast-write B copies.
__global__ __launch_bounds__(NT) void qim_fused(
    const float* __restrict__ a_p, const float* __restrict__ alpha_p,
    const float* __restrict__ k_p, const float* __restrict__ m_p,
    const float* __restrict__ delta, const float* __restrict__ E,
    const float* __restrict__ uar, const float* __restrict__ uai,
    const float* __restrict__ ubr, const float* __restrict__ ubi,
    float* __restrict__ ws, float* __restrict__ out, int copies)
{
    const QimCoef q = setup_coeffs(*a_p, *alpha_p, *k_p, *m_p,
                                   delta, E, uar, uai, ubr, ubi);
    const int base = blockIdx.x * (NT * CHUNKS * 4) + threadIdx.x * 4;

    float rr[CHUNKS][4];
    float lmin = FLT_BIG, lmax = -FLT_BIG;
#pragma unroll
    for (int c = 0; c < CHUNKS; ++c) {
        eval4(q, base + c * (NT * 4), rr[c]);
#pragma unroll
        for (int t = 0; t < 4; ++t) {
            lmin = fminf(lmin, rr[c][t]);
            lmax = fmaxf(lmax, rr[c][t]);
        }
    }
    float mn, mx;
    block_minmax(lmin, lmax, &mn, &mx);

    unsigned int* flags = (unsigned int*)(ws + 2 * NWG);
    if (threadIdx.x == 0) {
        ws[blockIdx.x]       = mn;
        ws[NWG + blockIdx.x] = mx;
        __threadfence();                                   // release partials
        __hip_atomic_store(&flags[blockIdx.x], SENT,
                           __ATOMIC_RELEASE, __HIP_MEMORY_SCOPE_AGENT);
    }

    // grid-wide wait: device-scope acquire loads (L1-bypassing), s_sleep
    // backoff. Safe: all blocks resident -> guaranteed progress.
    for (;;) {
        bool mine = true;
        for (int f = threadIdx.x; f < NWG; f += NT)
            mine &= (__hip_atomic_load(&flags[f], __ATOMIC_ACQUIRE,
                                       __HIP_MEMORY_SCOPE_AGENT) == SENT);
        if (__syncthreads_and(mine)) break;
        __builtin_amdgcn_s_sleep(16);
    }

    // every block folds all NWG partial pairs (acquire above makes them visible)
    float fmn = FLT_BIG, fmx = -FLT_BIG;
    for (int i = threadIdx.x; i < NWG; i += NT) {
        fmn = fminf(fmn, ws[i]);
        fmx = fmaxf(fmx, ws[NWG + i]);
    }
    float gmn, gmx;
    block_minmax(fmn, fmx, &gmn, &gmx);
    __shared__ float sg[2];
    if (threadIdx.x == 0) { sg[0] = gmn; sg[1] = 1.0f / (gmx - gmn + EPSF); }
    __syncthreads();
    const float gmin = sg[0], inv = sg[1];

#pragma unroll
    for (int c = 0; c < CHUNKS; ++c) {
        const int j0 = base + c * (NT * 4);
        float4 o;
        o.x = fmaf(rr[c][0] - gmin, inv, 0.5f);
        o.y = fmaf(rr[c][1] - gmin, inv, 0.5f);
        o.z = fmaf(rr[c][2] - gmin, inv, 0.5f);
        o.w = fmaf(rr[c][3] - gmin, inv, 0.5f);
        for (int b = 0; b < copies; ++b)
            *reinterpret_cast<float4*>(out + (size_t)b * L_TOT + j0) = o;
    }
}

extern "C" void kernel_launch(void* const* d_in, const int* in_sizes, int n_in,
                              void* d_out, int out_size, void* d_ws, size_t ws_size,
                              hipStream_t stream)
{
    const float* a_p     = (const float*)d_in[0];
    const float* alpha_p = (const float*)d_in[1];
    const float* k_p     = (const float*)d_in[2];
    const float* m_p     = (const float*)d_in[3];
    const float* delta   = (const float*)d_in[4];
    const float* E       = (const float*)d_in[5];
    const float* uar     = (const float*)d_in[6];
    const float* uai     = (const float*)d_in[7];
    const float* ubr     = (const float*)d_in[8];
    const float* ubi     = (const float*)d_in[9];
    float* out = (float*)d_out;
    float* wsf = (float*)d_ws;

    const int copies = out_size / L_TOT;  // == 4

    // Single graph node. Flags live in ws (0xAA-poisoned each call != SENT),
    // so no memset node is needed; blocks release their own flags.
    qim_fused<<<NWG, NT, 0, stream>>>(a_p, alpha_p, k_p, m_p, delta, E,
                                      uar, uai, ubr, ubi, wsf, out, copies);
}

// Round 14
// 165.668 us; speedup vs baseline: 1.0499x; 1.0499x over previous
//
#include <hip/hip_runtime.h>
#include <math.h>

// QIM1D single-node, single-writer sync.
// r = a*exp(-alpha*th)*sin(k*th)*cos(m*th) * |sum_i c_i*exp(i*w_i*th)|,
// minmax-normalized, +0.5, broadcast (B,1,L). L=2^21, B=4.
//
// Cross-round evidence: VALU work ~6us in every config; each dispatch carries
// ~25-40us invisible to all pipe counters; device-scope sync cost scales with
// writer x reader count (R7 +30us @2048 atomics, R10 ~0 @256, R11 +50us
// @512x512 spin). R12: ONE node, ONE writer block publishing {gmin,inv,flag}
// on one cache line; 255 reader blocks poll one line with s_sleep backoff.
// Deadlock-proof: readers never gate each other; 256 blocks x 16 waves =
// 4096 waves = half machine capacity -> all co-resident; and even without
// co-residency a queued reader sees the flag already set when it launches.
//
// Minmax on 64x-subsampled grid (anchors every 64 pts, eval4 covers 4):
// error <= |r'|max * 60h ~ 6e-4 << absmax tolerance floor 7.8e-3 (12x margin).

#define L_TOT   2097152
#define NT      1024
#define NWG     256
#define EPB     (L_TOT / NWG)     // 8192 elems per block
#define SUB     64
#define NANCH   (L_TOT / SUB)     // 32768 anchors; NANCH/NT = 32 per thread
#define EPSF    1e-8f
#define FLT_BIG 3.402823466e38f
#define SENT    0x51B0F00Du       // != 0xAAAAAAAA ws poison

struct QimCoef {
    float cr[6], ci[6], w[6];
    float a, alpha, k, m;
};

__device__ __forceinline__ QimCoef setup_coeffs(
    float a, float alpha, float k, float m,
    const float* __restrict__ delta, const float* __restrict__ E,
    const float* __restrict__ uar, const float* __restrict__ uai,
    const float* __restrict__ ubr, const float* __restrict__ ubi)
{
    QimCoef q;
    float na2 = 0.f, nb2 = 0.f;
    float ar[6], ai_[6], br[6], bi_[6];
#pragma unroll
    for (int i = 0; i < 6; ++i) {
        ar[i] = uar[i]; ai_[i] = uai[i]; br[i] = ubr[i]; bi_[i] = ubi[i];
        na2 = fmaf(ar[i], ar[i], fmaf(ai_[i], ai_[i], na2));
        nb2 = fmaf(br[i], br[i], fmaf(bi_[i], bi_[i], nb2));
    }
    const float s = 1.f / ((__fsqrt_rn(na2) + EPSF) * (__fsqrt_rn(nb2) + EPSF));
#pragma unroll
    for (int i = 0; i < 6; ++i) {
        q.cr[i] = (br[i] * ar[i] + bi_[i] * ai_[i]) * s;
        q.ci[i] = (bi_[i] * ar[i] - br[i] * ai_[i]) * s;
        q.w[i]  = -(2.f * E[i] + delta[i]);
    }
    q.a = a; q.alpha = alpha; q.k = k; q.m = m;
    return q;
}

// r at 4 consecutive grid points: native-trans anchors + 3 small-angle
// rotation steps (h ~ 4.8e-7: sin x = x, cos x = 1 - x^2/2, f32-exact).
__device__ __forceinline__ void eval4(const QimCoef& q, int j0, float r[4])
{
    const float h   = 1.0f / (float)(L_TOT - 1);
    const float th0 = (float)j0 * h;

    float sk = __sinf(q.k * th0), ck = __cosf(q.k * th0);
    float sm = __sinf(q.m * th0), cm = __cosf(q.m * th0);
    float e  = q.a * __expf(-q.alpha * th0);

    const float skh = q.k * h, ckh = fmaf(-0.5f * skh, skh, 1.0f);
    const float smh = q.m * h, cmh = fmaf(-0.5f * smh, smh, 1.0f);
    const float eh  = __expf(-q.alpha * h);

    float sw[6], cw[6], swh[6], cwh[6];
#pragma unroll
    for (int i = 0; i < 6; ++i) {
        const float ph = q.w[i] * th0;
        sw[i]  = __sinf(ph);
        cw[i]  = __cosf(ph);
        swh[i] = q.w[i] * h;
        cwh[i] = fmaf(-0.5f * swh[i], swh[i], 1.0f);
    }

#pragma unroll
    for (int t = 0; t < 4; ++t) {
        float re = 0.f, im = 0.f;
#pragma unroll
        for (int i = 0; i < 6; ++i) {
            re = fmaf(q.cr[i], cw[i], fmaf(-q.ci[i], sw[i], re));
            im = fmaf(q.cr[i], sw[i], fmaf( q.ci[i], cw[i], im));
        }
        const float S = __fsqrt_rn(fmaf(re, re, im * im));
        r[t] = e * sk * cm * S;

        if (t < 3) {
            e *= eh;
            float ns, nc;
            ns = fmaf(sk, ckh,  ck * skh); nc = fmaf(ck, ckh, -sk * skh); sk = ns; ck = nc;
            ns = fmaf(sm, cmh,  cm * smh); nc = fmaf(cm, cmh, -sm * smh); sm = ns; cm = nc;
#pragma unroll
            for (int i = 0; i < 6; ++i) {
                ns = fmaf(sw[i], cwh[i],  cw[i] * swh[i]);
                nc = fmaf(cw[i], cwh[i], -sw[i] * swh[i]);
                sw[i] = ns; cw[i] = nc;
            }
        }
    }
}

// Block-wide minmax for NT=1024 (16 waves).
__device__ __forceinline__ void block_minmax(float lmin, float lmax,
                                             float* out_min, float* out_max)
{
#pragma unroll
    for (int off = 32; off > 0; off >>= 1) {
        lmin = fminf(lmin, __shfl_down(lmin, off, 64));
        lmax = fmaxf(lmax, __shfl_down(lmax, off, 64));
    }
    __shared__ float smin[NT / 64], smax[NT / 64];
    const int lane = threadIdx.x & 63, wid = threadIdx.x >> 6;
    if (lane == 0) { smin[wid] = lmin; smax[wid] = lmax; }
    __syncthreads();
    if (threadIdx.x == 0) {
        float mn = smin[0], mx = smax[0];
#pragma unroll
        for (int i = 1; i < NT / 64; ++i) { mn = fminf(mn, smin[i]); mx = fmaxf(mx, smax[i]); }
        *out_min = mn; *out_max = mx;
    }
}

__global__ __launch_bounds__(NT, 4) void qim_fused_sw(
    const float* __restrict__ a_p, const float* __restrict__ alpha_p,
    const float* __restrict__ k_p, const float* __restrict__ m_p,
    const float* __restrict__ delta, const float* __restrict__ E,
    const float* __restrict__ uar, const float* __restrict__ uai,
    const float* __restrict__ ubr, const float* __restrict__ ubi,
    float* __restrict__ ws, float* __restrict__ out, int copies)
{
    const QimCoef q = setup_coeffs(*a_p, *alpha_p, *k_p, *m_p,
                                   delta, E, uar, uai, ubr, ubi);
    unsigned int* flag = (unsigned int*)(ws + 2);

    // ---- Block 0: subsampled global minmax, publish once -----------------
    if (blockIdx.x == 0) {
        float lmin = FLT_BIG, lmax = -FLT_BIG;
        for (int i = threadIdx.x; i < NANCH; i += NT) {   // 32 eval4/thread
            float r[4];
            eval4(q, i * SUB, r);
            lmin = fminf(lmin, fminf(fminf(r[0], r[1]), fminf(r[2], r[3])));
            lmax = fmaxf(lmax, fmaxf(fmaxf(r[0], r[1]), fmaxf(r[2], r[3])));
        }
        float gmn, gmx;
        block_minmax(lmin, lmax, &gmn, &gmx);
        if (threadIdx.x == 0) {
            ws[0] = gmn;
            ws[1] = 1.0f / (gmx - gmn + EPSF);
            __threadfence();                               // release data
            __hip_atomic_store(flag, SENT, __ATOMIC_RELEASE,
                               __HIP_MEMORY_SCOPE_AGENT);
        }
    }

    // ---- All blocks: eval own 8192-elem region into registers ------------
    const int base = blockIdx.x * EPB + threadIdx.x * 4;
    float rr[2][4];
    eval4(q, base,             rr[0]);
    eval4(q, base + NT * 4,    rr[1]);

    // ---- Wait for the broadcast (1 lane/block polls 1 line) --------------
    __shared__ float sg[2];
    if (threadIdx.x == 0) {
        while (__hip_atomic_load(flag, __ATOMIC_ACQUIRE,
                                 __HIP_MEMORY_SCOPE_AGENT) != SENT)
            __builtin_amdgcn_s_sleep(32);
        unsigned int u0 = __hip_atomic_load((unsigned int*)&ws[0],
                __ATOMIC_RELAXED, __HIP_MEMORY_SCOPE_AGENT);
        unsigned int u1 = __hip_atomic_load((unsigned int*)&ws[1],
                __ATOMIC_RELAXED, __HIP_MEMORY_SCOPE_AGENT);
        sg[0] = __uint_as_float(u0);
        sg[1] = __uint_as_float(u1);
    }
    __syncthreads();
    const float gmin = sg[0], inv = sg[1];

    // ---- Normalize from registers, broadcast-write B copies --------------
#pragma unroll
    for (int c = 0; c < 2; ++c) {
        const int j0 = base + c * (NT * 4);
        float4 o;
        o.x = fmaf(rr[c][0] - gmin, inv, 0.5f);
        o.y = fmaf(rr[c][1] - gmin, inv, 0.5f);
        o.z = fmaf(rr[c][2] - gmin, inv, 0.5f);
        o.w = fmaf(rr[c][3] - gmin, inv, 0.5f);
        for (int b = 0; b < copies; ++b)
            *reinterpret_cast<float4*>(out + (size_t)b * L_TOT + j0) = o;
    }
}

extern "C" void kernel_launch(void* const* d_in, const int* in_sizes, int n_in,
                              void* d_out, int out_size, void* d_ws, size_t ws_size,
                              hipStream_t stream)
{
    const float* a_p     = (const float*)d_in[0];
    const float* alpha_p = (const float*)d_in[1];
    const float* k_p     = (const float*)d_in[2];
    const float* m_p     = (const float*)d_in[3];
    const float* delta   = (const float*)d_in[4];
    const float* E       = (const float*)d_in[5];
    const float* uar     = (const float*)d_in[6];
    const float* uai     = (const float*)d_in[7];
    const float* ubr     = (const float*)d_in[8];
    const float* ubi     = (const float*)d_in[9];
    float* out = (float*)d_out;
    float* wsf = (float*)d_ws;

    const int copies = out_size / L_TOT;  // == 4

    // Single node. Flag lives in 0xAA-poisoned ws (!= SENT) -> no memset.
    qim_fused_sw<<<NWG, NT, 0, stream>>>(a_p, alpha_p, k_p, m_p, delta, E,
                                         uar, uai, ubr, ubi, wsf, out, copies);
}

// Round 15
// 132.105 us; speedup vs baseline: 1.3167x; 1.2541x over previous
//
#include <hip/hip_runtime.h>
#include <math.h>

// QIM1D single-node, distributed-minmax, tree sync.
// r = a*exp(-alpha*th)*sin(k*th)*cos(m*th) * |sum_i c_i*exp(i*w_i*th)|,
// minmax-normalized, +0.5, broadcast (B,1,L). L=2^21, B=4.
//
// R14 lesson: concentrating the minmax on block 0 serialized ~27-80us of
// eval onto ONE CU while 255 blocks slept (Occ 41%, VALUBusy 5.5%).
// R15: every block's local minmax is FREE (values already in registers).
// 256 partial stores + flags (R10-proven cheap) -> block 0 folds 256 pairs
// (<1us) -> single-line {gmin,inv,flag} broadcast (R14's reader side, fine).
// Exact minmax, no subsampling. Deadlock-safe: 4096 waves = half capacity.

#define L_TOT   2097152
#define NT      1024
#define NWG     256
#define EPB     (L_TOT / NWG)     // 8192 elems per block
#define EPSF    1e-8f
#define FLT_BIG 3.402823466e38f
#define SENT    0x51B0F00Du       // != 0xAAAAAAAA ws poison

// ws layout (floats): [0..NWG) mins | [NWG..2NWG) maxes |
//   [2NWG..3NWG) per-block flags (u32) | [3NWG] gmin | [3NWG+1] inv |
//   [3NWG+2] gflag (u32)
#define WS_MIN   0
#define WS_MAX   NWG
#define WS_FLAG  (2*NWG)
#define WS_GOUT  (3*NWG)
#define WS_GFLAG (3*NWG + 2)

struct QimCoef {
    float cr[6], ci[6], w[6];
    float a, alpha, k, m;
};

__device__ __forceinline__ QimCoef setup_coeffs(
    float a, float alpha, float k, float m,
    const float* __restrict__ delta, const float* __restrict__ E,
    const float* __restrict__ uar, const float* __restrict__ uai,
    const float* __restrict__ ubr, const float* __restrict__ ubi)
{
    QimCoef q;
    float na2 = 0.f, nb2 = 0.f;
    float ar[6], ai_[6], br[6], bi_[6];
#pragma unroll
    for (int i = 0; i < 6; ++i) {
        ar[i] = uar[i]; ai_[i] = uai[i]; br[i] = ubr[i]; bi_[i] = ubi[i];
        na2 = fmaf(ar[i], ar[i], fmaf(ai_[i], ai_[i], na2));
        nb2 = fmaf(br[i], br[i], fmaf(bi_[i], bi_[i], nb2));
    }
    const float s = 1.f / ((__fsqrt_rn(na2) + EPSF) * (__fsqrt_rn(nb2) + EPSF));
#pragma unroll
    for (int i = 0; i < 6; ++i) {
        q.cr[i] = (br[i] * ar[i] + bi_[i] * ai_[i]) * s;
        q.ci[i] = (bi_[i] * ar[i] - br[i] * ai_[i]) * s;
        q.w[i]  = -(2.f * E[i] + delta[i]);
    }
    q.a = a; q.alpha = alpha; q.k = k; q.m = m;
    return q;
}

// r at 4 consecutive grid points: native-trans anchors + 3 small-angle
// rotation steps (h ~ 4.8e-7: sin x = x, cos x = 1 - x^2/2, f32-exact).
__device__ __forceinline__ void eval4(const QimCoef& q, int j0, float r[4])
{
    const float h   = 1.0f / (float)(L_TOT - 1);
    const float th0 = (float)j0 * h;

    float sk = __sinf(q.k * th0), ck = __cosf(q.k * th0);
    float sm = __sinf(q.m * th0), cm = __cosf(q.m * th0);
    float e  = q.a * __expf(-q.alpha * th0);

    const float skh = q.k * h, ckh = fmaf(-0.5f * skh, skh, 1.0f);
    const float smh = q.m * h, cmh = fmaf(-0.5f * smh, smh, 1.0f);
    const float eh  = __expf(-q.alpha * h);

    float sw[6], cw[6], swh[6], cwh[6];
#pragma unroll
    for (int i = 0; i < 6; ++i) {
        const float ph = q.w[i] * th0;
        sw[i]  = __sinf(ph);
        cw[i]  = __cosf(ph);
        swh[i] = q.w[i] * h;
        cwh[i] = fmaf(-0.5f * swh[i], swh[i], 1.0f);
    }

#pragma unroll
    for (int t = 0; t < 4; ++t) {
        float re = 0.f, im = 0.f;
#pragma unroll
        for (int i = 0; i < 6; ++i) {
            re = fmaf(q.cr[i], cw[i], fmaf(-q.ci[i], sw[i], re));
            im = fmaf(q.cr[i], sw[i], fmaf( q.ci[i], cw[i], im));
        }
        const float S = __fsqrt_rn(fmaf(re, re, im * im));
        r[t] = e * sk * cm * S;

        if (t < 3) {
            e *= eh;
            float ns, nc;
            ns = fmaf(sk, ckh,  ck * skh); nc = fmaf(ck, ckh, -sk * skh); sk = ns; ck = nc;
            ns = fmaf(sm, cmh,  cm * smh); nc = fmaf(cm, cmh, -sm * smh); sm = ns; cm = nc;
#pragma unroll
            for (int i = 0; i < 6; ++i) {
                ns = fmaf(sw[i], cwh[i],  cw[i] * swh[i]);
                nc = fmaf(cw[i], cwh[i], -sw[i] * swh[i]);
                sw[i] = ns; cw[i] = nc;
            }
        }
    }
}

// Block-wide minmax (NT threads, 16 waves). Result in thread 0.
__device__ __forceinline__ void block_minmax(float lmin, float lmax,
                                             float* out_min, float* out_max)
{
#pragma unroll
    for (int off = 32; off > 0; off >>= 1) {
        lmin = fminf(lmin, __shfl_down(lmin, off, 64));
        lmax = fmaxf(lmax, __shfl_down(lmax, off, 64));
    }
    __shared__ float smin[NT / 64], smax[NT / 64];
    const int lane = threadIdx.x & 63, wid = threadIdx.x >> 6;
    if (lane == 0) { smin[wid] = lmin; smax[wid] = lmax; }
    __syncthreads();
    if (threadIdx.x == 0) {
        float mn = smin[0], mx = smax[0];
#pragma unroll
        for (int i = 1; i < NT / 64; ++i) { mn = fminf(mn, smin[i]); mx = fmaxf(mx, smax[i]); }
        *out_min = mn; *out_max = mx;
    }
}

__global__ __launch_bounds__(NT) void qim_fused_tree(
    const float* __restrict__ a_p, const float* __restrict__ alpha_p,
    const float* __restrict__ k_p, const float* __restrict__ m_p,
    const float* __restrict__ delta, const float* __restrict__ E,
    const float* __restrict__ uar, const float* __restrict__ uai,
    const float* __restrict__ ubr, const float* __restrict__ ubi,
    float* __restrict__ ws, float* __restrict__ out, int copies)
{
    const QimCoef q = setup_coeffs(*a_p, *alpha_p, *k_p, *m_p,
                                   delta, E, uar, uai, ubr, ubi);
    unsigned int* bflags = (unsigned int*)(ws + WS_FLAG);
    unsigned int* gflag  = (unsigned int*)(ws + WS_GFLAG);

    // ---- Phase 1: eval own region into registers; local minmax is free ---
    const int base = blockIdx.x * EPB + threadIdx.x * 4;
    float rr[2][4];
    eval4(q, base,          rr[0]);
    eval4(q, base + NT * 4, rr[1]);

    float lmin = FLT_BIG, lmax = -FLT_BIG;
#pragma unroll
    for (int c = 0; c < 2; ++c)
#pragma unroll
        for (int t = 0; t < 4; ++t) {
            lmin = fminf(lmin, rr[c][t]);
            lmax = fmaxf(lmax, rr[c][t]);
        }
    float mn, mx;
    block_minmax(lmin, lmax, &mn, &mx);

    if (threadIdx.x == 0) {
        ws[WS_MIN + blockIdx.x] = mn;
        ws[WS_MAX + blockIdx.x] = mx;
        __threadfence();                                   // release partials
        __hip_atomic_store(&bflags[blockIdx.x], SENT,
                           __ATOMIC_RELEASE, __HIP_MEMORY_SCOPE_AGENT);
    }

    // ---- Phase 2: block 0 folds 256 partials, publishes one line ---------
    __shared__ float sg[2];
    if (blockIdx.x == 0) {
        for (;;) {                       // threads 0..255 watch one flag each
            bool ok = true;
            if (threadIdx.x < NWG)
                ok = (__hip_atomic_load(&bflags[threadIdx.x], __ATOMIC_ACQUIRE,
                                        __HIP_MEMORY_SCOPE_AGENT) == SENT);
            if (__syncthreads_and(ok)) break;
            __builtin_amdgcn_s_sleep(2);
        }
        float fmn = FLT_BIG, fmx = -FLT_BIG;
        if (threadIdx.x < NWG) {
            fmn = ws[WS_MIN + threadIdx.x];
            fmx = ws[WS_MAX + threadIdx.x];
        }
        float gmn, gmx;
        block_minmax(fmn, fmx, &gmn, &gmx);
        if (threadIdx.x == 0) {
            const float inv = 1.0f / (gmx - gmn + EPSF);
            sg[0] = gmn; sg[1] = inv;
            ws[WS_GOUT]     = gmn;
            ws[WS_GOUT + 1] = inv;
            __threadfence();                               // release gout
            __hip_atomic_store(gflag, SENT, __ATOMIC_RELEASE,
                               __HIP_MEMORY_SCOPE_AGENT);
        }
        __syncthreads();
    } else {
        if (threadIdx.x == 0) {
            while (__hip_atomic_load(gflag, __ATOMIC_ACQUIRE,
                                     __HIP_MEMORY_SCOPE_AGENT) != SENT)
                __builtin_amdgcn_s_sleep(2);
            unsigned int u0 = __hip_atomic_load((unsigned int*)&ws[WS_GOUT],
                    __ATOMIC_RELAXED, __HIP_MEMORY_SCOPE_AGENT);
            unsigned int u1 = __hip_atomic_load((unsigned int*)&ws[WS_GOUT + 1],
                    __ATOMIC_RELAXED, __HIP_MEMORY_SCOPE_AGENT);
            sg[0] = __uint_as_float(u0);
            sg[1] = __uint_as_float(u1);
        }
        __syncthreads();
    }
    const float gmin = sg[0], inv = sg[1];

    // ---- Phase 3: normalize from registers, broadcast-write B copies -----
#pragma unroll
    for (int c = 0; c < 2; ++c) {
        const int j0 = base + c * (NT * 4);
        float4 o;
        o.x = fmaf(rr[c][0] - gmin, inv, 0.5f);
        o.y = fmaf(rr[c][1] - gmin, inv, 0.5f);
        o.z = fmaf(rr[c][2] - gmin, inv, 0.5f);
        o.w = fmaf(rr[c][3] - gmin, inv, 0.5f);
        for (int b = 0; b < copies; ++b)
            *reinterpret_cast<float4*>(out + (size_t)b * L_TOT + j0) = o;
    }
}

extern "C" void kernel_launch(void* const* d_in, const int* in_sizes, int n_in,
                              void* d_out, int out_size, void* d_ws, size_t ws_size,
                              hipStream_t stream)
{
    const float* a_p     = (const float*)d_in[0];
    const float* alpha_p = (const float*)d_in[1];
    const float* k_p     = (const float*)d_in[2];
    const float* m_p     = (const float*)d_in[3];
    const float* delta   = (const float*)d_in[4];
    const float* E       = (const float*)d_in[5];
    const float* uar     = (const float*)d_in[6];
    const float* uai     = (const float*)d_in[7];
    const float* ubr     = (const float*)d_in[8];
    const float* ubi     = (const float*)d_in[9];
    float* out = (float*)d_out;
    float* wsf = (float*)d_ws;

    const int copies = out_size / L_TOT;  // == 4

    // Single node. All flags live in 0xAA-poisoned ws (!= SENT) -> no memset.
    qim_fused_tree<<<NWG, NT, 0, stream>>>(a_p, alpha_p, k_p, m_p, delta, E,
                                           uar, uai, ubr, ubi, wsf, out, copies);
}